// Round 1
// baseline (148.788 us; speedup 1.0000x reference)
//
#include <hip/hip_runtime.h>
#include <math.h>

#define EPS 1e-4f
#define N_   32
#define CIN  128
#define L_   512
#define CP   64
#define P_   2000
#define NCLS 200

// ---------------- Kernel 1: conv1x1 -> relu -> conv1x1 -> sigmoid, + sum(f^2) ----------------
__global__ __launch_bounds__(256) void k1_conv(const float* __restrict__ x,
    const float* __restrict__ W1, const float* __restrict__ b1,
    const float* __restrict__ W2, const float* __restrict__ b2,
    float* __restrict__ fbuf, float* __restrict__ x2buf)
{
    __shared__ float4 W1s[64][32];   // [o][c4]
    __shared__ float4 W2s[64][16];   // [o][c4]
    __shared__ float  hS[64][65];    // [c][l] padded
    __shared__ float  x2p[4][64];
    __shared__ float  b1s[64], b2s[64];

    const int tid = threadIdx.x;
    const int n   = blockIdx.y;
    const int lg  = blockIdx.x;

    const float4* W1g = (const float4*)W1;
    #pragma unroll
    for (int i = 0; i < 8; ++i) {
        int idx = tid + i*256;
        W1s[idx >> 5][idx & 31] = W1g[idx];
    }
    const float4* W2g = (const float4*)W2;
    #pragma unroll
    for (int i = 0; i < 4; ++i) {
        int idx = tid + i*256;
        W2s[idx >> 4][idx & 15] = W2g[idx];
    }
    if (tid < 64) { b1s[tid] = b1[tid]; b2s[tid] = b2[tid]; }
    __syncthreads();

    const int lloc = tid & 63;
    const int og   = tid >> 6;      // 0..3, 16 output channels each
    const int l    = lg*64 + lloc;

    float h[16];
    #pragma unroll
    for (int o = 0; o < 16; ++o) h[o] = b1s[og*16 + o];

    const float* xp = x + (size_t)n*CIN*L_ + l;
    #pragma unroll 4
    for (int c4 = 0; c4 < 32; ++c4) {
        float xv0 = xp[(c4*4+0)*L_];
        float xv1 = xp[(c4*4+1)*L_];
        float xv2 = xp[(c4*4+2)*L_];
        float xv3 = xp[(c4*4+3)*L_];
        #pragma unroll
        for (int o = 0; o < 16; ++o) {
            float4 w = W1s[og*16+o][c4];
            h[o] = fmaf(w.x, xv0, fmaf(w.y, xv1, fmaf(w.z, xv2, fmaf(w.w, xv3, h[o]))));
        }
    }
    #pragma unroll
    for (int o = 0; o < 16; ++o)
        hS[og*16+o][lloc] = fmaxf(h[o], 0.0f);
    __syncthreads();

    float f[16];
    #pragma unroll
    for (int o = 0; o < 16; ++o) f[o] = b2s[og*16 + o];
    #pragma unroll 4
    for (int c4 = 0; c4 < 16; ++c4) {
        float h0 = hS[c4*4+0][lloc];
        float h1 = hS[c4*4+1][lloc];
        float h2 = hS[c4*4+2][lloc];
        float h3 = hS[c4*4+3][lloc];
        #pragma unroll
        for (int o = 0; o < 16; ++o) {
            float4 w = W2s[og*16+o][c4];
            f[o] = fmaf(w.x, h0, fmaf(w.y, h1, fmaf(w.z, h2, fmaf(w.w, h3, f[o]))));
        }
    }
    float s = 0.0f;
    #pragma unroll
    for (int o = 0; o < 16; ++o) {
        float v = 1.0f / (1.0f + expf(-f[o]));
        fbuf[((size_t)n*CP + og*16+o)*L_ + l] = v;
        s = fmaf(v, v, s);
    }
    x2p[og][lloc] = s;
    __syncthreads();
    if (tid < 64)
        x2buf[n*L_ + lg*64 + tid] = x2p[0][tid] + x2p[1][tid] + x2p[2][tid] + x2p[3][tid];
}

// ---------------- Kernel 2: fused distance GEMM + min over L + activation ----------------
// block: one n, 128-prototype tile; loops 4 chunks of 128 l positions.
__global__ __launch_bounds__(256) void k2_dist(const float* __restrict__ fbuf,
    const float* __restrict__ x2buf, const float* __restrict__ proto,
    float* __restrict__ md_out, float* __restrict__ acts)
{
    __shared__ float protoS[64][128];  // [k][p]
    __shared__ float fS[64][128];      // [k][l]
    __shared__ float redS[16][128];
    __shared__ float p2S[128];
    __shared__ float x2S[128];

    const int tid = threadIdx.x;
    const int n   = blockIdx.y;
    const int p0  = blockIdx.x * 128;

    // stage prototype tile, transposed to k-major
    {
        int pl   = tid & 127;
        int half = tid >> 7;
        int gp   = p0 + pl;
        const float* pg = proto + (size_t)gp*64;
        #pragma unroll
        for (int q = 0; q < 8; ++q) {
            int kq = half*8 + q;
            float4 v = make_float4(0.f, 0.f, 0.f, 0.f);
            if (gp < P_) v = *(const float4*)(pg + kq*4);
            protoS[kq*4+0][pl] = v.x;
            protoS[kq*4+1][pl] = v.y;
            protoS[kq*4+2][pl] = v.z;
            protoS[kq*4+3][pl] = v.w;
        }
    }
    __syncthreads();
    if (tid < 128) {
        float s = 0.f;
        #pragma unroll
        for (int k = 0; k < 64; ++k) { float v = protoS[k][tid]; s = fmaf(v, v, s); }
        p2S[tid] = s;
    }

    const int lane = tid & 63;
    const int wave = tid >> 6;
    const int pb = (wave & 1)*64 + (lane & 7)*8;   // 8 prototypes
    const int lb = (wave >> 1)*64 + (lane >> 3)*8; // 8 l positions

    float rmin[8];
    #pragma unroll
    for (int i = 0; i < 8; ++i) rmin[i] = 3.0e38f;

    for (int ch = 0; ch < 4; ++ch) {
        __syncthreads();
        const int l0 = ch*128;
        {   // stage f chunk [64 c][128 l], coalesced
            int ll4 = tid & 31;
            int c0  = tid >> 5;
            #pragma unroll
            for (int cc = 0; cc < 8; ++cc) {
                int c = c0*8 + cc;
                float4 v = *(const float4*)(fbuf + ((size_t)n*CP + c)*L_ + l0 + ll4*4);
                *(float4*)&fS[c][ll4*4] = v;
            }
        }
        if (tid < 128) x2S[tid] = x2buf[n*L_ + l0 + tid];
        __syncthreads();

        float acc[8][8];
        #pragma unroll
        for (int i = 0; i < 8; ++i)
            #pragma unroll
            for (int j = 0; j < 8; ++j) acc[i][j] = 0.f;

        #pragma unroll 4
        for (int k = 0; k < 64; ++k) {
            float4 a0  = *(const float4*)&protoS[k][pb];
            float4 a1  = *(const float4*)&protoS[k][pb+4];
            float4 b0  = *(const float4*)&fS[k][lb];
            float4 b1v = *(const float4*)&fS[k][lb+4];
            float av[8] = {a0.x,a0.y,a0.z,a0.w,a1.x,a1.y,a1.z,a1.w};
            float bv[8] = {b0.x,b0.y,b0.z,b0.w,b1v.x,b1v.y,b1v.z,b1v.w};
            #pragma unroll
            for (int i = 0; i < 8; ++i)
                #pragma unroll
                for (int j = 0; j < 8; ++j)
                    acc[i][j] = fmaf(av[i], bv[j], acc[i][j]);
        }
        #pragma unroll
        for (int j = 0; j < 8; ++j) {
            float xv = x2S[lb + j];
            #pragma unroll
            for (int i = 0; i < 8; ++i) {
                float cand = fmaf(-2.f, acc[i][j], xv);
                rmin[i] = fminf(rmin[i], cand);
            }
        }
    }

    const int row = (wave >> 1)*8 + (lane >> 3);
    #pragma unroll
    for (int i = 0; i < 8; ++i) redS[row][pb + i] = rmin[i];
    __syncthreads();
    if (tid < 128) {
        float mv = 3.0e38f;
        #pragma unroll
        for (int r = 0; r < 16; ++r) mv = fminf(mv, redS[r][tid]);
        float m = fmaxf(mv + p2S[tid], 0.0f);
        int gp = p0 + tid;
        if (gp < P_) {
            md_out[n*P_ + gp] = m;
            acts[n*P_ + gp]   = logf((m + 1.0f) / (m + EPS));
        }
    }
}

// ---------------- Kernel 3: logits = acts @ last_w^T ----------------
__global__ __launch_bounds__(256) void k3_logits(const float* __restrict__ acts,
    const float* __restrict__ last_w, float* __restrict__ out)
{
    int idx = blockIdx.x*256 + threadIdx.x;   // 0..6399
    int cls = idx >> 5;
    int n   = idx & 31;
    const float4* a = (const float4*)(acts + (size_t)n*P_);
    const float4* w = (const float4*)(last_w + (size_t)cls*P_);
    float acc = 0.f;
    for (int p4 = 0; p4 < P_/4; ++p4) {
        float4 av = a[p4]; float4 wv = w[p4];
        acc += av.x*wv.x + av.y*wv.y + av.z*wv.z + av.w*wv.w;
    }
    out[n*NCLS + cls] = acc;
}

extern "C" void kernel_launch(void* const* d_in, const int* in_sizes, int n_in,
                              void* d_out, int out_size, void* d_ws, size_t ws_size,
                              hipStream_t stream)
{
    const float* x      = (const float*)d_in[0];
    const float* W1     = (const float*)d_in[1];
    const float* b1     = (const float*)d_in[2];
    const float* W2     = (const float*)d_in[3];
    const float* b2     = (const float*)d_in[4];
    const float* proto  = (const float*)d_in[5];
    const float* last_w = (const float*)d_in[6];

    float* out   = (float*)d_out;             // [32*200] logits, then [32*2000] min_dist
    float* fbuf  = (float*)d_ws;              // 32*64*512 f32 = 4.19 MB
    float* x2buf = fbuf + (size_t)N_*CP*L_;   // 32*512 f32
    float* acts  = x2buf + N_*L_;             // 32*2000 f32

    k1_conv  <<<dim3(8, 32),  256, 0, stream>>>(x, W1, b1, W2, b2, fbuf, x2buf);
    k2_dist  <<<dim3(16, 32), 256, 0, stream>>>(fbuf, x2buf, proto, out + N_*NCLS, acts);
    k3_logits<<<25,           256, 0, stream>>>(acts, last_w, out);
}

// Round 2
// 90.343 us; speedup vs baseline: 1.6469x; 1.6469x over previous
//
#include <hip/hip_runtime.h>
#include <math.h>

#define EPS 1e-4f
#define N_   32
#define CIN  128
#define L_   512
#define CP   64
#define P_   2000
#define NCLS 200

// ---------------- Kernel 1: conv1x1 -> relu -> conv1x1 -> sigmoid, + sum(f^2) ----------------
__global__ __launch_bounds__(256) void k1_conv(const float* __restrict__ x,
    const float* __restrict__ W1, const float* __restrict__ b1,
    const float* __restrict__ W2, const float* __restrict__ b2,
    float* __restrict__ fbuf, float* __restrict__ x2buf)
{
    __shared__ float4 W1s[64][32];   // [o][c4]
    __shared__ float4 W2s[64][16];   // [o][c4]
    __shared__ float  hS[64][65];    // [c][l] padded
    __shared__ float  x2p[4][64];
    __shared__ float  b1s[64], b2s[64];

    const int tid = threadIdx.x;
    const int n   = blockIdx.y;
    const int lg  = blockIdx.x;

    const float4* W1g = (const float4*)W1;
    #pragma unroll
    for (int i = 0; i < 8; ++i) {
        int idx = tid + i*256;
        W1s[idx >> 5][idx & 31] = W1g[idx];
    }
    const float4* W2g = (const float4*)W2;
    #pragma unroll
    for (int i = 0; i < 4; ++i) {
        int idx = tid + i*256;
        W2s[idx >> 4][idx & 15] = W2g[idx];
    }
    if (tid < 64) { b1s[tid] = b1[tid]; b2s[tid] = b2[tid]; }
    __syncthreads();

    const int lloc = tid & 63;
    const int og   = tid >> 6;      // 0..3, 16 output channels each
    const int l    = lg*64 + lloc;

    float h[16];
    #pragma unroll
    for (int o = 0; o < 16; ++o) h[o] = b1s[og*16 + o];

    const float* xp = x + (size_t)n*CIN*L_ + l;
    #pragma unroll 4
    for (int c4 = 0; c4 < 32; ++c4) {
        float xv0 = xp[(c4*4+0)*L_];
        float xv1 = xp[(c4*4+1)*L_];
        float xv2 = xp[(c4*4+2)*L_];
        float xv3 = xp[(c4*4+3)*L_];
        #pragma unroll
        for (int o = 0; o < 16; ++o) {
            float4 w = W1s[og*16+o][c4];
            h[o] = fmaf(w.x, xv0, fmaf(w.y, xv1, fmaf(w.z, xv2, fmaf(w.w, xv3, h[o]))));
        }
    }
    #pragma unroll
    for (int o = 0; o < 16; ++o)
        hS[og*16+o][lloc] = fmaxf(h[o], 0.0f);
    __syncthreads();

    float f[16];
    #pragma unroll
    for (int o = 0; o < 16; ++o) f[o] = b2s[og*16 + o];
    #pragma unroll 4
    for (int c4 = 0; c4 < 16; ++c4) {
        float h0 = hS[c4*4+0][lloc];
        float h1 = hS[c4*4+1][lloc];
        float h2 = hS[c4*4+2][lloc];
        float h3 = hS[c4*4+3][lloc];
        #pragma unroll
        for (int o = 0; o < 16; ++o) {
            float4 w = W2s[og*16+o][c4];
            f[o] = fmaf(w.x, h0, fmaf(w.y, h1, fmaf(w.z, h2, fmaf(w.w, h3, f[o]))));
        }
    }
    float s = 0.0f;
    #pragma unroll
    for (int o = 0; o < 16; ++o) {
        float v = 1.0f / (1.0f + expf(-f[o]));
        fbuf[((size_t)n*CP + og*16+o)*L_ + l] = v;
        s = fmaf(v, v, s);
    }
    x2p[og][lloc] = s;
    __syncthreads();
    if (tid < 64)
        x2buf[n*L_ + lg*64 + tid] = x2p[0][tid] + x2p[1][tid] + x2p[2][tid] + x2p[3][tid];
}

// ---------------- Kernel 2: fused distance GEMM + min over L + activation ----------------
// block: one n, 128-prototype tile; loops 4 chunks of 128 l positions.
__global__ __launch_bounds__(256) void k2_dist(const float* __restrict__ fbuf,
    const float* __restrict__ x2buf, const float* __restrict__ proto,
    float* __restrict__ md_out, float* __restrict__ acts)
{
    __shared__ float protoS[64][128];  // [k][p]
    __shared__ float fS[64][128];      // [k][l]
    __shared__ float redS[16][128];
    __shared__ float p2S[128];
    __shared__ float x2S[128];

    const int tid = threadIdx.x;
    const int n   = blockIdx.y;
    const int p0  = blockIdx.x * 128;

    // stage prototype tile, transposed to k-major
    {
        int pl   = tid & 127;
        int half = tid >> 7;
        int gp   = p0 + pl;
        const float* pg = proto + (size_t)gp*64;
        #pragma unroll
        for (int q = 0; q < 8; ++q) {
            int kq = half*8 + q;
            float4 v = make_float4(0.f, 0.f, 0.f, 0.f);
            if (gp < P_) v = *(const float4*)(pg + kq*4);
            protoS[kq*4+0][pl] = v.x;
            protoS[kq*4+1][pl] = v.y;
            protoS[kq*4+2][pl] = v.z;
            protoS[kq*4+3][pl] = v.w;
        }
    }
    __syncthreads();
    if (tid < 128) {
        float s = 0.f;
        #pragma unroll
        for (int k = 0; k < 64; ++k) { float v = protoS[k][tid]; s = fmaf(v, v, s); }
        p2S[tid] = s;
    }

    const int lane = tid & 63;
    const int wave = tid >> 6;
    const int pb = (wave & 1)*64 + (lane & 7)*8;   // 8 prototypes
    const int lb = (wave >> 1)*64 + (lane >> 3)*8; // 8 l positions

    float rmin[8];
    #pragma unroll
    for (int i = 0; i < 8; ++i) rmin[i] = 3.0e38f;

    for (int ch = 0; ch < 4; ++ch) {
        __syncthreads();
        const int l0 = ch*128;
        {   // stage f chunk [64 c][128 l], coalesced
            int ll4 = tid & 31;
            int c0  = tid >> 5;
            #pragma unroll
            for (int cc = 0; cc < 8; ++cc) {
                int c = c0*8 + cc;
                float4 v = *(const float4*)(fbuf + ((size_t)n*CP + c)*L_ + l0 + ll4*4);
                *(float4*)&fS[c][ll4*4] = v;
            }
        }
        if (tid < 128) x2S[tid] = x2buf[n*L_ + l0 + tid];
        __syncthreads();

        float acc[8][8];
        #pragma unroll
        for (int i = 0; i < 8; ++i)
            #pragma unroll
            for (int j = 0; j < 8; ++j) acc[i][j] = 0.f;

        #pragma unroll 4
        for (int k = 0; k < 64; ++k) {
            float4 a0  = *(const float4*)&protoS[k][pb];
            float4 a1  = *(const float4*)&protoS[k][pb+4];
            float4 b0  = *(const float4*)&fS[k][lb];
            float4 b1v = *(const float4*)&fS[k][lb+4];
            float av[8] = {a0.x,a0.y,a0.z,a0.w,a1.x,a1.y,a1.z,a1.w};
            float bv[8] = {b0.x,b0.y,b0.z,b0.w,b1v.x,b1v.y,b1v.z,b1v.w};
            #pragma unroll
            for (int i = 0; i < 8; ++i)
                #pragma unroll
                for (int j = 0; j < 8; ++j)
                    acc[i][j] = fmaf(av[i], bv[j], acc[i][j]);
        }
        #pragma unroll
        for (int j = 0; j < 8; ++j) {
            float xv = x2S[lb + j];
            #pragma unroll
            for (int i = 0; i < 8; ++i) {
                float cand = fmaf(-2.f, acc[i][j], xv);
                rmin[i] = fminf(rmin[i], cand);
            }
        }
    }

    const int row = (wave >> 1)*8 + (lane >> 3);
    #pragma unroll
    for (int i = 0; i < 8; ++i) redS[row][pb + i] = rmin[i];
    __syncthreads();
    if (tid < 128) {
        float mv = 3.0e38f;
        #pragma unroll
        for (int r = 0; r < 16; ++r) mv = fminf(mv, redS[r][tid]);
        float m = fmaxf(mv + p2S[tid], 0.0f);
        int gp = p0 + tid;
        if (gp < P_) {
            md_out[n*P_ + gp] = m;
            acts[n*P_ + gp]   = logf((m + 1.0f) / (m + EPS));
        }
    }
}

// ---------------- Kernel 3: logits = acts @ last_w^T, one wave per output ----------------
__global__ __launch_bounds__(256) void k3_logits(const float* __restrict__ acts,
    const float* __restrict__ last_w, float* __restrict__ out)
{
    const int wid  = (blockIdx.x * 256 + threadIdx.x) >> 6;  // 0..6399
    const int lane = threadIdx.x & 63;
    const int n    = wid / NCLS;
    const int cls  = wid - n * NCLS;

    const float4* a = (const float4*)(acts + (size_t)n*P_);
    const float4* w = (const float4*)(last_w + (size_t)cls*P_);

    float acc = 0.f;
    #pragma unroll
    for (int it = 0; it < 8; ++it) {
        int idx = it*64 + lane;          // float4 index, 0..511
        if (idx < P_/4) {
            float4 av = a[idx]; float4 wv = w[idx];
            acc += av.x*wv.x + av.y*wv.y + av.z*wv.z + av.w*wv.w;
        }
    }
    #pragma unroll
    for (int off = 32; off > 0; off >>= 1)
        acc += __shfl_down(acc, off);
    if (lane == 0)
        out[n*NCLS + cls] = acc;
}

extern "C" void kernel_launch(void* const* d_in, const int* in_sizes, int n_in,
                              void* d_out, int out_size, void* d_ws, size_t ws_size,
                              hipStream_t stream)
{
    const float* x      = (const float*)d_in[0];
    const float* W1     = (const float*)d_in[1];
    const float* b1     = (const float*)d_in[2];
    const float* W2     = (const float*)d_in[3];
    const float* b2     = (const float*)d_in[4];
    const float* proto  = (const float*)d_in[5];
    const float* last_w = (const float*)d_in[6];

    float* out   = (float*)d_out;             // [32*200] logits, then [32*2000] min_dist
    float* fbuf  = (float*)d_ws;              // 32*64*512 f32 = 4.19 MB
    float* x2buf = fbuf + (size_t)N_*CP*L_;   // 32*512 f32
    float* acts  = x2buf + N_*L_;             // 32*2000 f32

    k1_conv  <<<dim3(8, 32),  256, 0, stream>>>(x, W1, b1, W2, b2, fbuf, x2buf);
    k2_dist  <<<dim3(16, 32), 256, 0, stream>>>(fbuf, x2buf, proto, out + N_*NCLS, acts);
    k3_logits<<<1600,         256, 0, stream>>>(acts, last_w, out);
}

// Round 3
// 68.278 us; speedup vs baseline: 2.1792x; 1.3232x over previous
//
#include <hip/hip_runtime.h>
#include <math.h>

#define EPS 1e-4f
#define N_   32
#define CIN  128
#define L_   512
#define CP   64
#define P_   2000
#define NCLS 200

typedef __attribute__((ext_vector_type(8))) short bf16x8;
typedef __attribute__((ext_vector_type(4))) float f32x4;

__device__ inline unsigned short f2bf_rne(float f) {
    unsigned int u = __float_as_uint(f);
    unsigned int r = u + 0x7FFFu + ((u >> 16) & 1u);
    return (unsigned short)(r >> 16);
}
__device__ inline float bf2f(unsigned short h) {
    return __uint_as_float(((unsigned int)h) << 16);
}

// ---------------- Kernel 1: conv1x1 -> relu -> conv1x1 -> sigmoid ----------------
// outputs: fT hi/lo bf16 in [n][l][c] layout, x2 = sum_c f^2 in f32
__global__ __launch_bounds__(256) void k1_conv(const float* __restrict__ x,
    const float* __restrict__ W1, const float* __restrict__ b1,
    const float* __restrict__ W2, const float* __restrict__ b2,
    unsigned short* __restrict__ fTh, unsigned short* __restrict__ fTl,
    float* __restrict__ x2buf)
{
    __shared__ float4 W1s[64][32];   // [o][c4]
    __shared__ float4 W2s[64][16];   // [o][c4]
    __shared__ float  hS[64][65];    // [c][l] padded
    __shared__ float  x2p[4][64];
    __shared__ float  b1s[64], b2s[64];

    const int tid = threadIdx.x;
    const int n   = blockIdx.y;
    const int lg  = blockIdx.x;

    const float4* W1g = (const float4*)W1;
    #pragma unroll
    for (int i = 0; i < 8; ++i) {
        int idx = tid + i*256;
        W1s[idx >> 5][idx & 31] = W1g[idx];
    }
    const float4* W2g = (const float4*)W2;
    #pragma unroll
    for (int i = 0; i < 4; ++i) {
        int idx = tid + i*256;
        W2s[idx >> 4][idx & 15] = W2g[idx];
    }
    if (tid < 64) { b1s[tid] = b1[tid]; b2s[tid] = b2[tid]; }
    __syncthreads();

    const int lloc = tid & 63;
    const int og   = tid >> 6;      // 0..3, 16 output channels each
    const int l    = lg*64 + lloc;

    float h[16];
    #pragma unroll
    for (int o = 0; o < 16; ++o) h[o] = b1s[og*16 + o];

    const float* xp = x + (size_t)n*CIN*L_ + l;
    #pragma unroll 4
    for (int c4 = 0; c4 < 32; ++c4) {
        float xv0 = xp[(c4*4+0)*L_];
        float xv1 = xp[(c4*4+1)*L_];
        float xv2 = xp[(c4*4+2)*L_];
        float xv3 = xp[(c4*4+3)*L_];
        #pragma unroll
        for (int o = 0; o < 16; ++o) {
            float4 w = W1s[og*16+o][c4];
            h[o] = fmaf(w.x, xv0, fmaf(w.y, xv1, fmaf(w.z, xv2, fmaf(w.w, xv3, h[o]))));
        }
    }
    #pragma unroll
    for (int o = 0; o < 16; ++o)
        hS[og*16+o][lloc] = fmaxf(h[o], 0.0f);
    __syncthreads();

    float f[16];
    #pragma unroll
    for (int o = 0; o < 16; ++o) f[o] = b2s[og*16 + o];
    #pragma unroll 4
    for (int c4 = 0; c4 < 16; ++c4) {
        float h0 = hS[c4*4+0][lloc];
        float h1 = hS[c4*4+1][lloc];
        float h2 = hS[c4*4+2][lloc];
        float h3 = hS[c4*4+3][lloc];
        #pragma unroll
        for (int o = 0; o < 16; ++o) {
            float4 w = W2s[og*16+o][c4];
            f[o] = fmaf(w.x, h0, fmaf(w.y, h1, fmaf(w.z, h2, fmaf(w.w, h3, f[o]))));
        }
    }

    unsigned int packH[8], packL[8];
    float s = 0.0f;
    #pragma unroll
    for (int o = 0; o < 16; ++o) {
        float v = 1.0f / (1.0f + expf(-f[o]));
        unsigned short hb = f2bf_rne(v);
        unsigned short lb = f2bf_rne(v - bf2f(hb));
        if (o & 1) { packH[o>>1] |= ((unsigned)hb) << 16; packL[o>>1] |= ((unsigned)lb) << 16; }
        else       { packH[o>>1] = hb;                     packL[o>>1] = lb; }
        s = fmaf(v, v, s);
    }
    size_t u4 = ((size_t)(n*L_ + l))*8 + og*2;   // uint4 index: [n][l][c] * 2B / 16B
    ((uint4*)fTh)[u4]   = make_uint4(packH[0],packH[1],packH[2],packH[3]);
    ((uint4*)fTh)[u4+1] = make_uint4(packH[4],packH[5],packH[6],packH[7]);
    ((uint4*)fTl)[u4]   = make_uint4(packL[0],packL[1],packL[2],packL[3]);
    ((uint4*)fTl)[u4+1] = make_uint4(packL[4],packL[5],packL[6],packL[7]);

    x2p[og][lloc] = s;
    __syncthreads();
    if (tid < 64)
        x2buf[n*L_ + lg*64 + tid] = x2p[0][tid] + x2p[1][tid] + x2p[2][tid] + x2p[3][tid];
}

// ---------------- Kernel 2: split-bf16 MFMA distance scan + min + activation ----------------
// block: one n x 128-proto tile; proto frags in registers; f staged in swizzled LDS.
__global__ __launch_bounds__(256, 2) void k2_dist(
    const unsigned short* __restrict__ fTh, const unsigned short* __restrict__ fTl,
    const float* __restrict__ x2buf, const float* __restrict__ proto,
    float* __restrict__ md_out, float* __restrict__ acts)
{
    __shared__ unsigned short fBh[8192];  // [128 l][64 k] bf16, XOR-swizzled rows (16KB)
    __shared__ unsigned short fBl[8192];
    __shared__ float x2S[128];
    __shared__ float redS[4][128];

    const int tid  = threadIdx.x;
    const int lane = tid & 63;
    const int wv   = tid >> 6;
    const int n    = blockIdx.y;
    const int p0   = blockIdx.x * 128;

    // ---- A fragments: proto f32 -> split bf16, kept in registers ----
    bf16x8 ah[8][2], al[8][2];
    {
        const int pr = lane & 15;
        const int g  = lane >> 4;
        #pragma unroll
        for (int ps = 0; ps < 8; ++ps) {
            int p = p0 + ps*16 + pr;
            #pragma unroll
            for (int ks = 0; ks < 2; ++ks) {
                float v[8];
                if (p < P_) {
                    const float4* src = (const float4*)(proto + (size_t)p*64 + ks*32 + g*8);
                    float4 a0 = src[0], a1 = src[1];
                    v[0]=a0.x; v[1]=a0.y; v[2]=a0.z; v[3]=a0.w;
                    v[4]=a1.x; v[5]=a1.y; v[6]=a1.z; v[7]=a1.w;
                } else {
                    #pragma unroll
                    for (int j = 0; j < 8; ++j) v[j] = 0.f;
                }
                bf16x8 H, Lo;
                #pragma unroll
                for (int j = 0; j < 8; ++j) {
                    unsigned short hb = f2bf_rne(v[j]);
                    unsigned short lb = f2bf_rne(v[j] - bf2f(hb));
                    H[j] = (short)hb; Lo[j] = (short)lb;
                }
                ah[ps][ks] = H; al[ps][ks] = Lo;
            }
        }
    }

    float rmin[8][4];
    #pragma unroll
    for (int ps = 0; ps < 8; ++ps)
        #pragma unroll
        for (int r = 0; r < 4; ++r) rmin[ps][r] = 3.0e38f;

    const char* gH = (const char*)(fTh + (size_t)n*L_*CP);
    const char* gL = (const char*)(fTl + (size_t)n*L_*CP);

    for (int ch = 0; ch < 4; ++ch) {
        __syncthreads();
        // stage 16KB per buffer: LDS[l*128 + (b ^ ((l&7)<<4))] = global[l*128 + b]
        #pragma unroll
        for (int s4 = 0; s4 < 4; ++s4) {
            int d  = (s4*256 + tid) * 16;
            int lr = d >> 7;
            int bo = d & 127;
            int ph = (lr << 7) + (bo ^ ((lr & 7) << 4));
            uint4 vh = *(const uint4*)(gH + (size_t)ch*16384 + d);
            uint4 vl = *(const uint4*)(gL + (size_t)ch*16384 + d);
            *(uint4*)((char*)fBh + ph) = vh;
            *(uint4*)((char*)fBl + ph) = vl;
        }
        if (tid < 128) x2S[tid] = x2buf[n*L_ + ch*128 + tid];
        __syncthreads();

        #pragma unroll
        for (int ls = 0; ls < 2; ++ls) {
            const int lsub = wv*2 + ls;
            const int lrow = lsub*16 + (lane & 15);
            const int g    = lane >> 4;
            bf16x8 bh[2], bl[2];
            #pragma unroll
            for (int ks = 0; ks < 2; ++ks) {
                int bo = (ks*64 + g*16) ^ ((lrow & 7) << 4);
                bh[ks] = *(const bf16x8*)((const char*)fBh + lrow*128 + bo);
                bl[ks] = *(const bf16x8*)((const char*)fBl + lrow*128 + bo);
            }
            float xv = x2S[lsub*16 + (lane & 15)];
            #pragma unroll
            for (int ps = 0; ps < 8; ++ps) {
                f32x4 c = {0.f, 0.f, 0.f, 0.f};
                c = __builtin_amdgcn_mfma_f32_16x16x32_bf16(ah[ps][0], bh[0], c, 0, 0, 0);
                c = __builtin_amdgcn_mfma_f32_16x16x32_bf16(ah[ps][1], bh[1], c, 0, 0, 0);
                c = __builtin_amdgcn_mfma_f32_16x16x32_bf16(al[ps][0], bh[0], c, 0, 0, 0);
                c = __builtin_amdgcn_mfma_f32_16x16x32_bf16(al[ps][1], bh[1], c, 0, 0, 0);
                c = __builtin_amdgcn_mfma_f32_16x16x32_bf16(ah[ps][0], bl[0], c, 0, 0, 0);
                c = __builtin_amdgcn_mfma_f32_16x16x32_bf16(ah[ps][1], bl[1], c, 0, 0, 0);
                #pragma unroll
                for (int r = 0; r < 4; ++r)
                    rmin[ps][r] = fminf(rmin[ps][r], fmaf(-2.f, c[r], xv));
            }
        }
    }

    // min over the 16 l-columns within each 16-lane group
    #pragma unroll
    for (int ps = 0; ps < 8; ++ps)
        #pragma unroll
        for (int r = 0; r < 4; ++r) {
            float v = rmin[ps][r];
            v = fminf(v, __shfl_xor(v, 1));
            v = fminf(v, __shfl_xor(v, 2));
            v = fminf(v, __shfl_xor(v, 4));
            v = fminf(v, __shfl_xor(v, 8));
            rmin[ps][r] = v;
        }
    if ((lane & 15) == 0) {
        const int g = lane >> 4;
        #pragma unroll
        for (int ps = 0; ps < 8; ++ps)
            #pragma unroll
            for (int r = 0; r < 4; ++r)
                redS[wv][ps*16 + g*4 + r] = rmin[ps][r];
    }
    __syncthreads();
    if (tid < 128) {
        float mv = fminf(fminf(redS[0][tid], redS[1][tid]), fminf(redS[2][tid], redS[3][tid]));
        int gp = p0 + tid;
        if (gp < P_) {
            const float4* pr = (const float4*)(proto + (size_t)gp*64);
            float p2 = 0.f;
            #pragma unroll
            for (int q = 0; q < 16; ++q) {
                float4 v = pr[q];
                p2 += v.x*v.x + v.y*v.y + v.z*v.z + v.w*v.w;
            }
            float m = fmaxf(mv + p2, 0.0f);
            md_out[n*P_ + gp] = m;
            acts[n*P_ + gp]   = logf((m + 1.0f) / (m + EPS));
        }
    }
}

// ---------------- Kernel 3: logits = acts @ last_w^T, one wave per output ----------------
__global__ __launch_bounds__(256) void k3_logits(const float* __restrict__ acts,
    const float* __restrict__ last_w, float* __restrict__ out)
{
    const int wid  = (blockIdx.x * 256 + threadIdx.x) >> 6;  // 0..6399
    const int lane = threadIdx.x & 63;
    const int n    = wid / NCLS;
    const int cls  = wid - n * NCLS;

    const float4* a = (const float4*)(acts + (size_t)n*P_);
    const float4* w = (const float4*)(last_w + (size_t)cls*P_);

    float acc = 0.f;
    #pragma unroll
    for (int it = 0; it < 8; ++it) {
        int idx = it*64 + lane;          // float4 index, 0..511
        if (idx < P_/4) {
            float4 av = a[idx]; float4 wv = w[idx];
            acc += av.x*wv.x + av.y*wv.y + av.z*wv.z + av.w*wv.w;
        }
    }
    #pragma unroll
    for (int off = 32; off > 0; off >>= 1)
        acc += __shfl_down(acc, off);
    if (lane == 0)
        out[n*NCLS + cls] = acc;
}

extern "C" void kernel_launch(void* const* d_in, const int* in_sizes, int n_in,
                              void* d_out, int out_size, void* d_ws, size_t ws_size,
                              hipStream_t stream)
{
    const float* x      = (const float*)d_in[0];
    const float* W1     = (const float*)d_in[1];
    const float* b1     = (const float*)d_in[2];
    const float* W2     = (const float*)d_in[3];
    const float* b2     = (const float*)d_in[4];
    const float* proto  = (const float*)d_in[5];
    const float* last_w = (const float*)d_in[6];

    float* out = (float*)d_out;   // [32*200] logits, then [32*2000] min_dist

    // ws layout: fTh 2MB | fTl 2MB | x2buf 64KB | acts 256KB  (total ~4.32MB)
    unsigned short* fTh = (unsigned short*)d_ws;
    unsigned short* fTl = fTh + (size_t)N_*L_*CP;
    float* x2buf = (float*)(fTl + (size_t)N_*L_*CP);
    float* acts  = x2buf + (size_t)N_*L_;

    k1_conv  <<<dim3(8, 32),  256, 0, stream>>>(x, W1, b1, W2, b2, fTh, fTl, x2buf);
    k2_dist  <<<dim3(16, 32), 256, 0, stream>>>(fTh, fTl, x2buf, proto, out + N_*NCLS, acts);
    k3_logits<<<1600,         256, 0, stream>>>(acts, last_w, out);
}

// Round 4
// 64.793 us; speedup vs baseline: 2.2964x; 1.0538x over previous
//
#include <hip/hip_runtime.h>
#include <math.h>

#define EPS 1e-4f
#define N_   32
#define CIN  128
#define L_   512
#define CP   64
#define P_   2000
#define NCLS 200

typedef __attribute__((ext_vector_type(8))) short bf16x8;
typedef __attribute__((ext_vector_type(4))) float f32x4;

__device__ inline unsigned short f2bf_rne(float f) {
    unsigned int u = __float_as_uint(f);
    unsigned int r = u + 0x7FFFu + ((u >> 16) & 1u);
    return (unsigned short)(r >> 16);
}
__device__ inline float bf2f(unsigned short h) {
    return __uint_as_float(((unsigned int)h) << 16);
}

__device__ inline void gl_lds16(const void* g, void* l) {
    __builtin_amdgcn_global_load_lds(
        (const __attribute__((address_space(1))) unsigned int*)g,
        (__attribute__((address_space(3))) unsigned int*)l, 16, 0, 0);
}

// ---------------- Kernel 1: conv1x1 -> relu -> conv1x1 -> sigmoid ----------------
// x staged in LDS (async), W in LDS (uniform broadcast reads), packed bf16 hi/lo
// outputs coalesced via swizzled LDS bounce. Outputs fT hi/lo in [n][l][c], x2 f32.
__global__ __launch_bounds__(256) void k1_conv(const float* __restrict__ x,
    const float* __restrict__ W1, const float* __restrict__ b1,
    const float* __restrict__ W2, const float* __restrict__ b2,
    unsigned short* __restrict__ fTh, unsigned short* __restrict__ fTl,
    float* __restrict__ x2buf)
{
    __shared__ float  xS[128*64];    // [c][l] 32KB
    __shared__ float4 W1s[64][32];   // [o][c4] 32KB
    __shared__ float4 W2s[64][16];   // [o][c4] 16KB
    __shared__ float  hS[64][65];    // [c][l] padded 16.6KB
    __shared__ uint4  fPH[64][8];    // [l][u4] swizzled 8KB
    __shared__ uint4  fPL[64][8];    // 8KB
    __shared__ float  x2p[4][64];
    __shared__ float  b1s[64], b2s[64];

    const int tid  = threadIdx.x;
    const int lane = tid & 63;
    const int wv   = tid >> 6;
    const int n    = blockIdx.y;
    const int lg   = blockIdx.x;

    // ---- async stage x tile [128 c][64 l] into LDS (issue first: overlap W staging) ----
    {
        const float* xbase = x + (size_t)n*CIN*L_ + lg*64;
        #pragma unroll
        for (int i = 0; i < 8; ++i) {
            int r = wv*8 + i;                       // row-block of 4 c-rows
            const float* src = xbase + (size_t)(r*4 + (lane >> 4))*L_ + (lane & 15)*4;
            gl_lds16(src, &xS[r*256]);
        }
    }

    const float4* W1g = (const float4*)W1;
    #pragma unroll
    for (int i = 0; i < 8; ++i) {
        int idx = tid + i*256;
        W1s[idx >> 5][idx & 31] = W1g[idx];
    }
    const float4* W2g = (const float4*)W2;
    #pragma unroll
    for (int i = 0; i < 4; ++i) {
        int idx = tid + i*256;
        W2s[idx >> 4][idx & 15] = W2g[idx];
    }
    if (tid < 64) { b1s[tid] = b1[tid]; b2s[tid] = b2[tid]; }
    __syncthreads();

    const int lloc = lane;
    const int og   = wv;            // 0..3, 16 output channels each

    float h[16];
    #pragma unroll
    for (int o = 0; o < 16; ++o) h[o] = b1s[og*16 + o];

    #pragma unroll 8
    for (int c4 = 0; c4 < 32; ++c4) {
        float xv0 = xS[(c4*4+0)*64 + lloc];
        float xv1 = xS[(c4*4+1)*64 + lloc];
        float xv2 = xS[(c4*4+2)*64 + lloc];
        float xv3 = xS[(c4*4+3)*64 + lloc];
        #pragma unroll
        for (int o = 0; o < 16; ++o) {
            float4 w = W1s[og*16+o][c4];
            h[o] = fmaf(w.x, xv0, fmaf(w.y, xv1, fmaf(w.z, xv2, fmaf(w.w, xv3, h[o]))));
        }
    }
    #pragma unroll
    for (int o = 0; o < 16; ++o)
        hS[og*16+o][lloc] = fmaxf(h[o], 0.0f);
    __syncthreads();

    float f[16];
    #pragma unroll
    for (int o = 0; o < 16; ++o) f[o] = b2s[og*16 + o];
    #pragma unroll 4
    for (int c4 = 0; c4 < 16; ++c4) {
        float h0 = hS[c4*4+0][lloc];
        float h1 = hS[c4*4+1][lloc];
        float h2 = hS[c4*4+2][lloc];
        float h3 = hS[c4*4+3][lloc];
        #pragma unroll
        for (int o = 0; o < 16; ++o) {
            float4 w = W2s[og*16+o][c4];
            f[o] = fmaf(w.x, h0, fmaf(w.y, h1, fmaf(w.z, h2, fmaf(w.w, h3, f[o]))));
        }
    }

    unsigned int packH[8], packL[8];
    float s = 0.0f;
    #pragma unroll
    for (int o = 0; o < 16; ++o) {
        float v = 1.0f / (1.0f + expf(-f[o]));
        unsigned short hb = f2bf_rne(v);
        unsigned short lb = f2bf_rne(v - bf2f(hb));
        if (o & 1) { packH[o>>1] |= ((unsigned)hb) << 16; packL[o>>1] |= ((unsigned)lb) << 16; }
        else       { packH[o>>1] = hb;                     packL[o>>1] = lb; }
        s = fmaf(v, v, s);
    }
    // swizzled LDS bounce for coalesced global stores
    fPH[lloc][(og*2+0) ^ (lloc & 7)] = make_uint4(packH[0],packH[1],packH[2],packH[3]);
    fPH[lloc][(og*2+1) ^ (lloc & 7)] = make_uint4(packH[4],packH[5],packH[6],packH[7]);
    fPL[lloc][(og*2+0) ^ (lloc & 7)] = make_uint4(packL[0],packL[1],packL[2],packL[3]);
    fPL[lloc][(og*2+1) ^ (lloc & 7)] = make_uint4(packL[4],packL[5],packL[6],packL[7]);
    x2p[og][lloc] = s;
    __syncthreads();

    uint4* gH4 = (uint4*)fTh + ((size_t)(n*L_ + lg*64))*8;
    uint4* gL4 = (uint4*)fTl + ((size_t)(n*L_ + lg*64))*8;
    #pragma unroll
    for (int it = 0; it < 2; ++it) {
        int idx = it*256 + tid;      // 0..511
        int l = idx >> 3, u = idx & 7;
        gH4[idx] = fPH[l][u ^ (l & 7)];
        gL4[idx] = fPL[l][u ^ (l & 7)];
    }
    if (tid < 64)
        x2buf[n*L_ + lg*64 + tid] = x2p[0][tid] + x2p[1][tid] + x2p[2][tid] + x2p[3][tid];
}

// ---------------- Kernel 2: split-bf16 MFMA distance scan + min + activation ----------------
__global__ __launch_bounds__(256, 2) void k2_dist(
    const unsigned short* __restrict__ fTh, const unsigned short* __restrict__ fTl,
    const float* __restrict__ x2buf, const float* __restrict__ proto,
    float* __restrict__ md_out, float* __restrict__ acts)
{
    __shared__ unsigned short fBh[8192];  // [128 l][64 k] bf16, XOR-swizzled rows (16KB)
    __shared__ unsigned short fBl[8192];
    __shared__ float x2S[128];
    __shared__ float redS[4][128];

    const int tid  = threadIdx.x;
    const int lane = tid & 63;
    const int wv   = tid >> 6;
    const int n    = blockIdx.y;
    const int p0   = blockIdx.x * 128;

    // ---- A fragments: proto f32 -> split bf16, kept in registers ----
    bf16x8 ah[8][2], al[8][2];
    {
        const int pr = lane & 15;
        const int g  = lane >> 4;
        #pragma unroll
        for (int ps = 0; ps < 8; ++ps) {
            int p = p0 + ps*16 + pr;
            #pragma unroll
            for (int ks = 0; ks < 2; ++ks) {
                float v[8];
                if (p < P_) {
                    const float4* src = (const float4*)(proto + (size_t)p*64 + ks*32 + g*8);
                    float4 a0 = src[0], a1 = src[1];
                    v[0]=a0.x; v[1]=a0.y; v[2]=a0.z; v[3]=a0.w;
                    v[4]=a1.x; v[5]=a1.y; v[6]=a1.z; v[7]=a1.w;
                } else {
                    #pragma unroll
                    for (int j = 0; j < 8; ++j) v[j] = 0.f;
                }
                bf16x8 H, Lo;
                #pragma unroll
                for (int j = 0; j < 8; ++j) {
                    unsigned short hb = f2bf_rne(v[j]);
                    unsigned short lb = f2bf_rne(v[j] - bf2f(hb));
                    H[j] = (short)hb; Lo[j] = (short)lb;
                }
                ah[ps][ks] = H; al[ps][ks] = Lo;
            }
        }
    }

    float rmin[8][4];
    #pragma unroll
    for (int ps = 0; ps < 8; ++ps)
        #pragma unroll
        for (int r = 0; r < 4; ++r) rmin[ps][r] = 3.0e38f;

    const char* gH = (const char*)(fTh + (size_t)n*L_*CP);
    const char* gL = (const char*)(fTl + (size_t)n*L_*CP);

    for (int ch = 0; ch < 4; ++ch) {
        __syncthreads();
        // stage 16KB per buffer: LDS[l*128 + (b ^ ((l&7)<<4))] = global[l*128 + b]
        #pragma unroll
        for (int s4 = 0; s4 < 4; ++s4) {
            int d  = (s4*256 + tid) * 16;
            int lr = d >> 7;
            int bo = d & 127;
            int ph = (lr << 7) + (bo ^ ((lr & 7) << 4));
            uint4 vh = *(const uint4*)(gH + (size_t)ch*16384 + d);
            uint4 vl = *(const uint4*)(gL + (size_t)ch*16384 + d);
            *(uint4*)((char*)fBh + ph) = vh;
            *(uint4*)((char*)fBl + ph) = vl;
        }
        if (tid < 128) x2S[tid] = x2buf[n*L_ + ch*128 + tid];
        __syncthreads();

        #pragma unroll
        for (int ls = 0; ls < 2; ++ls) {
            const int lsub = wv*2 + ls;
            const int lrow = lsub*16 + (lane & 15);
            const int g    = lane >> 4;
            bf16x8 bh[2], bl[2];
            #pragma unroll
            for (int ks = 0; ks < 2; ++ks) {
                int bo = (ks*64 + g*16) ^ ((lrow & 7) << 4);
                bh[ks] = *(const bf16x8*)((const char*)fBh + lrow*128 + bo);
                bl[ks] = *(const bf16x8*)((const char*)fBl + lrow*128 + bo);
            }
            float xv = x2S[lsub*16 + (lane & 15)];
            #pragma unroll
            for (int ps = 0; ps < 8; ++ps) {
                f32x4 c = {0.f, 0.f, 0.f, 0.f};
                c = __builtin_amdgcn_mfma_f32_16x16x32_bf16(ah[ps][0], bh[0], c, 0, 0, 0);
                c = __builtin_amdgcn_mfma_f32_16x16x32_bf16(ah[ps][1], bh[1], c, 0, 0, 0);
                c = __builtin_amdgcn_mfma_f32_16x16x32_bf16(al[ps][0], bh[0], c, 0, 0, 0);
                c = __builtin_amdgcn_mfma_f32_16x16x32_bf16(al[ps][1], bh[1], c, 0, 0, 0);
                c = __builtin_amdgcn_mfma_f32_16x16x32_bf16(ah[ps][0], bl[0], c, 0, 0, 0);
                c = __builtin_amdgcn_mfma_f32_16x16x32_bf16(ah[ps][1], bl[1], c, 0, 0, 0);
                #pragma unroll
                for (int r = 0; r < 4; ++r)
                    rmin[ps][r] = fminf(rmin[ps][r], fmaf(-2.f, c[r], xv));
            }
        }
    }

    // min over the 16 l-columns within each 16-lane group
    #pragma unroll
    for (int ps = 0; ps < 8; ++ps)
        #pragma unroll
        for (int r = 0; r < 4; ++r) {
            float v = rmin[ps][r];
            v = fminf(v, __shfl_xor(v, 1));
            v = fminf(v, __shfl_xor(v, 2));
            v = fminf(v, __shfl_xor(v, 4));
            v = fminf(v, __shfl_xor(v, 8));
            rmin[ps][r] = v;
        }
    if ((lane & 15) == 0) {
        const int g = lane >> 4;
        #pragma unroll
        for (int ps = 0; ps < 8; ++ps)
            #pragma unroll
            for (int r = 0; r < 4; ++r)
                redS[wv][ps*16 + g*4 + r] = rmin[ps][r];
    }
    __syncthreads();
    if (tid < 128) {
        float mv = fminf(fminf(redS[0][tid], redS[1][tid]), fminf(redS[2][tid], redS[3][tid]));
        int gp = p0 + tid;
        if (gp < P_) {
            const float4* pr = (const float4*)(proto + (size_t)gp*64);
            float p2 = 0.f;
            #pragma unroll
            for (int q = 0; q < 16; ++q) {
                float4 v = pr[q];
                p2 += v.x*v.x + v.y*v.y + v.z*v.z + v.w*v.w;
            }
            float m = fmaxf(mv + p2, 0.0f);
            md_out[n*P_ + gp] = m;
            acts[n*P_ + gp]   = logf((m + 1.0f) / (m + EPS));
        }
    }
}

// ---------------- Kernel 3: logits = acts @ last_w^T, one wave per output ----------------
__global__ __launch_bounds__(256) void k3_logits(const float* __restrict__ acts,
    const float* __restrict__ last_w, float* __restrict__ out)
{
    const int wid  = (blockIdx.x * 256 + threadIdx.x) >> 6;  // 0..6399
    const int lane = threadIdx.x & 63;
    const int n    = wid / NCLS;
    const int cls  = wid - n * NCLS;

    const float4* a = (const float4*)(acts + (size_t)n*P_);
    const float4* w = (const float4*)(last_w + (size_t)cls*P_);

    float acc = 0.f;
    #pragma unroll
    for (int it = 0; it < 8; ++it) {
        int idx = it*64 + lane;          // float4 index, 0..511
        if (idx < P_/4) {
            float4 av = a[idx]; float4 wv = w[idx];
            acc += av.x*wv.x + av.y*wv.y + av.z*wv.z + av.w*wv.w;
        }
    }
    #pragma unroll
    for (int off = 32; off > 0; off >>= 1)
        acc += __shfl_down(acc, off);
    if (lane == 0)
        out[n*NCLS + cls] = acc;
}

extern "C" void kernel_launch(void* const* d_in, const int* in_sizes, int n_in,
                              void* d_out, int out_size, void* d_ws, size_t ws_size,
                              hipStream_t stream)
{
    const float* x      = (const float*)d_in[0];
    const float* W1     = (const float*)d_in[1];
    const float* b1     = (const float*)d_in[2];
    const float* W2     = (const float*)d_in[3];
    const float* b2     = (const float*)d_in[4];
    const float* proto  = (const float*)d_in[5];
    const float* last_w = (const float*)d_in[6];

    float* out = (float*)d_out;   // [32*200] logits, then [32*2000] min_dist

    // ws layout: fTh 2MB | fTl 2MB | x2buf 64KB | acts 256KB
    unsigned short* fTh = (unsigned short*)d_ws;
    unsigned short* fTl = fTh + (size_t)N_*L_*CP;
    float* x2buf = (float*)(fTl + (size_t)N_*L_*CP);
    float* acts  = x2buf + (size_t)N_*L_;

    k1_conv  <<<dim3(8, 32),  256, 0, stream>>>(x, W1, b1, W2, b2, fTh, fTl, x2buf);
    k2_dist  <<<dim3(16, 32), 256, 0, stream>>>(fTh, fTl, x2buf, proto, out + N_*NCLS, acts);
    k3_logits<<<1600,         256, 0, stream>>>(acts, last_w, out);
}

// Round 5
// 54.828 us; speedup vs baseline: 2.7137x; 1.1817x over previous
//
#include <hip/hip_runtime.h>
#include <math.h>

#define EPS 1e-4f
#define N_   32
#define CIN  128
#define L_   512
#define CP   64
#define P_   2000
#define NCLS 200

typedef __attribute__((ext_vector_type(8))) short bf16x8;
typedef __attribute__((ext_vector_type(4))) float f32x4;

__device__ inline unsigned short f2bf_rne(float f) {
    unsigned int u = __float_as_uint(f);
    unsigned int r = u + 0x7FFFu + ((u >> 16) & 1u);
    return (unsigned short)(r >> 16);
}
__device__ inline float bf2f(unsigned short h) {
    return __uint_as_float(((unsigned int)h) << 16);
}

__device__ inline void gl_lds16(const void* g, void* l) {
    __builtin_amdgcn_global_load_lds(
        (const __attribute__((address_space(1))) unsigned int*)g,
        (__attribute__((address_space(3))) unsigned int*)l, 16, 0, 0);
}

// ---------------- Kernel 1: conv1x1 -> relu -> conv1x1 -> sigmoid ----------------
// 512 blocks (2/CU): block = (n, 32 l). thread = (og: 8-ch group, l).
// LDS ~74KB -> 2 blocks/CU. hS overlaid with store-bounce buffer.
__global__ __launch_bounds__(256) void k1_conv(const float* __restrict__ x,
    const float* __restrict__ W1, const float* __restrict__ b1,
    const float* __restrict__ W2, const float* __restrict__ b2,
    unsigned short* __restrict__ fTh, unsigned short* __restrict__ fTl,
    float* __restrict__ x2buf)
{
    __shared__ float  xS[128*32];              // 16KB [c][l]
    __shared__ float4 W1s[64][32];             // 32KB [o][c4]
    __shared__ float4 W2s[64][16];             // 16KB [o][c4]
    __shared__ __align__(16) char scratch[8448];  // hS [64][33] f32  OR  fP [2][32][8] uint4
    __shared__ float  x2p[8][32];
    __shared__ float  b1s[64], b2s[64];

    float (*hS)[33]       = (float (*)[33])scratch;
    uint4 (*fP)[32][8]    = (uint4 (*)[32][8])scratch;

    const int tid = threadIdx.x;
    const int wv  = tid >> 6;
    const int n   = blockIdx.y;
    const int lg  = blockIdx.x;

    // ---- async stage x tile [128 c][32 l] into LDS (16 instrs, 4/wave) ----
    {
        const float* xbase = x + (size_t)n*CIN*L_ + lg*32;
        const int lane = tid & 63;
        #pragma unroll
        for (int i = 0; i < 4; ++i) {
            int blk = wv*4 + i;                 // 1KB chunk = 8 c-rows
            const float* src = xbase + (size_t)(blk*8 + (lane >> 3))*L_ + (lane & 7)*4;
            gl_lds16(src, &xS[blk*256]);
        }
    }

    const float4* W1g = (const float4*)W1;
    #pragma unroll
    for (int i = 0; i < 8; ++i) {
        int idx = tid + i*256;
        W1s[idx >> 5][idx & 31] = W1g[idx];
    }
    const float4* W2g = (const float4*)W2;
    #pragma unroll
    for (int i = 0; i < 4; ++i) {
        int idx = tid + i*256;
        W2s[idx >> 4][idx & 15] = W2g[idx];
    }
    if (tid < 64) { b1s[tid] = b1[tid]; b2s[tid] = b2[tid]; }
    __syncthreads();

    const int l  = tid & 31;
    const int og = tid >> 5;        // 0..7, 8 output channels each

    float h[8];
    #pragma unroll
    for (int o = 0; o < 8; ++o) h[o] = b1s[og*8 + o];

    #pragma unroll 8
    for (int c4 = 0; c4 < 32; ++c4) {
        float xv0 = xS[(c4*4+0)*32 + l];
        float xv1 = xS[(c4*4+1)*32 + l];
        float xv2 = xS[(c4*4+2)*32 + l];
        float xv3 = xS[(c4*4+3)*32 + l];
        #pragma unroll
        for (int o = 0; o < 8; ++o) {
            float4 w = W1s[og*8+o][c4];
            h[o] = fmaf(w.x, xv0, fmaf(w.y, xv1, fmaf(w.z, xv2, fmaf(w.w, xv3, h[o]))));
        }
    }
    __syncthreads();   // xS done; scratch free to use as hS
    #pragma unroll
    for (int o = 0; o < 8; ++o)
        hS[og*8+o][l] = fmaxf(h[o], 0.0f);
    __syncthreads();

    float f[8];
    #pragma unroll
    for (int o = 0; o < 8; ++o) f[o] = b2s[og*8 + o];
    #pragma unroll 4
    for (int c4 = 0; c4 < 16; ++c4) {
        float h0 = hS[c4*4+0][l];
        float h1 = hS[c4*4+1][l];
        float h2 = hS[c4*4+2][l];
        float h3 = hS[c4*4+3][l];
        #pragma unroll
        for (int o = 0; o < 8; ++o) {
            float4 w = W2s[og*8+o][c4];
            f[o] = fmaf(w.x, h0, fmaf(w.y, h1, fmaf(w.z, h2, fmaf(w.w, h3, f[o]))));
        }
    }

    unsigned int packH[4], packL[4];
    float s = 0.0f;
    #pragma unroll
    for (int o = 0; o < 8; ++o) {
        float v = 1.0f / (1.0f + expf(-f[o]));
        unsigned short hb = f2bf_rne(v);
        unsigned short lb = f2bf_rne(v - bf2f(hb));
        if (o & 1) { packH[o>>1] |= ((unsigned)hb) << 16; packL[o>>1] |= ((unsigned)lb) << 16; }
        else       { packH[o>>1] = hb;                     packL[o>>1] = lb; }
        s = fmaf(v, v, s);
    }
    x2p[og][l] = s;
    __syncthreads();   // hS reads done; scratch reused as fP bounce

    fP[0][l][og ^ (l & 7)] = make_uint4(packH[0],packH[1],packH[2],packH[3]);
    fP[1][l][og ^ (l & 7)] = make_uint4(packL[0],packL[1],packL[2],packL[3]);
    __syncthreads();

    // coalesced stores: [n][l][c] bf16, 64 c per l = 8 uint4
    uint4* gH4 = (uint4*)fTh + ((size_t)(n*L_ + lg*32))*8;
    uint4* gL4 = (uint4*)fTl + ((size_t)(n*L_ + lg*32))*8;
    {
        int ll = tid >> 3, u = tid & 7;
        gH4[tid] = fP[0][ll][u ^ (ll & 7)];
        gL4[tid] = fP[1][ll][u ^ (ll & 7)];
    }
    if (tid < 32) {
        float v = 0.f;
        #pragma unroll
        for (int g = 0; g < 8; ++g) v += x2p[g][tid];
        x2buf[n*L_ + lg*32 + tid] = v;
    }
}

// ---------------- Kernel 2: split-bf16 MFMA distance scan + min + activation ----------------
__global__ __launch_bounds__(256, 2) void k2_dist(
    const unsigned short* __restrict__ fTh, const unsigned short* __restrict__ fTl,
    const float* __restrict__ x2buf, const float* __restrict__ proto,
    float* __restrict__ md_out, float* __restrict__ acts)
{
    __shared__ unsigned short fBh[8192];  // [128 l][64 k] bf16, XOR-swizzled rows (16KB)
    __shared__ unsigned short fBl[8192];
    __shared__ float x2S[128];
    __shared__ float redS[4][128];

    const int tid  = threadIdx.x;
    const int lane = tid & 63;
    const int wv   = tid >> 6;
    const int n    = blockIdx.y;
    const int p0   = blockIdx.x * 128;

    // ---- A fragments: proto f32 -> split bf16, kept in registers ----
    bf16x8 ah[8][2], al[8][2];
    {
        const int pr = lane & 15;
        const int g  = lane >> 4;
        #pragma unroll
        for (int ps = 0; ps < 8; ++ps) {
            int p = p0 + ps*16 + pr;
            #pragma unroll
            for (int ks = 0; ks < 2; ++ks) {
                float v[8];
                if (p < P_) {
                    const float4* src = (const float4*)(proto + (size_t)p*64 + ks*32 + g*8);
                    float4 a0 = src[0], a1 = src[1];
                    v[0]=a0.x; v[1]=a0.y; v[2]=a0.z; v[3]=a0.w;
                    v[4]=a1.x; v[5]=a1.y; v[6]=a1.z; v[7]=a1.w;
                } else {
                    #pragma unroll
                    for (int j = 0; j < 8; ++j) v[j] = 0.f;
                }
                bf16x8 H, Lo;
                #pragma unroll
                for (int j = 0; j < 8; ++j) {
                    unsigned short hb = f2bf_rne(v[j]);
                    unsigned short lb = f2bf_rne(v[j] - bf2f(hb));
                    H[j] = (short)hb; Lo[j] = (short)lb;
                }
                ah[ps][ks] = H; al[ps][ks] = Lo;
            }
        }
    }

    float rmin[8][4];
    #pragma unroll
    for (int ps = 0; ps < 8; ++ps)
        #pragma unroll
        for (int r = 0; r < 4; ++r) rmin[ps][r] = 3.0e38f;

    const char* gH = (const char*)(fTh + (size_t)n*L_*CP);
    const char* gL = (const char*)(fTl + (size_t)n*L_*CP);

    for (int ch = 0; ch < 4; ++ch) {
        __syncthreads();
        // stage 16KB per buffer: LDS[l*128 + (b ^ ((l&7)<<4))] = global[l*128 + b]
        #pragma unroll
        for (int s4 = 0; s4 < 4; ++s4) {
            int d  = (s4*256 + tid) * 16;
            int lr = d >> 7;
            int bo = d & 127;
            int ph = (lr << 7) + (bo ^ ((lr & 7) << 4));
            uint4 vh = *(const uint4*)(gH + (size_t)ch*16384 + d);
            uint4 vl = *(const uint4*)(gL + (size_t)ch*16384 + d);
            *(uint4*)((char*)fBh + ph) = vh;
            *(uint4*)((char*)fBl + ph) = vl;
        }
        if (tid < 128) x2S[tid] = x2buf[n*L_ + ch*128 + tid];
        __syncthreads();

        #pragma unroll
        for (int ls = 0; ls < 2; ++ls) {
            const int lsub = wv*2 + ls;
            const int lrow = lsub*16 + (lane & 15);
            const int g    = lane >> 4;
            bf16x8 bh[2], bl[2];
            #pragma unroll
            for (int ks = 0; ks < 2; ++ks) {
                int bo = (ks*64 + g*16) ^ ((lrow & 7) << 4);
                bh[ks] = *(const bf16x8*)((const char*)fBh + lrow*128 + bo);
                bl[ks] = *(const bf16x8*)((const char*)fBl + lrow*128 + bo);
            }
            float xv = x2S[lsub*16 + (lane & 15)];
            #pragma unroll
            for (int ps = 0; ps < 8; ++ps) {
                f32x4 c = {0.f, 0.f, 0.f, 0.f};
                c = __builtin_amdgcn_mfma_f32_16x16x32_bf16(ah[ps][0], bh[0], c, 0, 0, 0);
                c = __builtin_amdgcn_mfma_f32_16x16x32_bf16(ah[ps][1], bh[1], c, 0, 0, 0);
                c = __builtin_amdgcn_mfma_f32_16x16x32_bf16(al[ps][0], bh[0], c, 0, 0, 0);
                c = __builtin_amdgcn_mfma_f32_16x16x32_bf16(al[ps][1], bh[1], c, 0, 0, 0);
                c = __builtin_amdgcn_mfma_f32_16x16x32_bf16(ah[ps][0], bl[0], c, 0, 0, 0);
                c = __builtin_amdgcn_mfma_f32_16x16x32_bf16(ah[ps][1], bl[1], c, 0, 0, 0);
                #pragma unroll
                for (int r = 0; r < 4; ++r)
                    rmin[ps][r] = fminf(rmin[ps][r], fmaf(-2.f, c[r], xv));
            }
        }
    }

    // min over the 16 l-columns within each 16-lane group
    #pragma unroll
    for (int ps = 0; ps < 8; ++ps)
        #pragma unroll
        for (int r = 0; r < 4; ++r) {
            float v = rmin[ps][r];
            v = fminf(v, __shfl_xor(v, 1));
            v = fminf(v, __shfl_xor(v, 2));
            v = fminf(v, __shfl_xor(v, 4));
            v = fminf(v, __shfl_xor(v, 8));
            rmin[ps][r] = v;
        }
    if ((lane & 15) == 0) {
        const int g = lane >> 4;
        #pragma unroll
        for (int ps = 0; ps < 8; ++ps)
            #pragma unroll
            for (int r = 0; r < 4; ++r)
                redS[wv][ps*16 + g*4 + r] = rmin[ps][r];
    }
    __syncthreads();
    if (tid < 128) {
        float mv = fminf(fminf(redS[0][tid], redS[1][tid]), fminf(redS[2][tid], redS[3][tid]));
        int gp = p0 + tid;
        if (gp < P_) {
            const float4* pr = (const float4*)(proto + (size_t)gp*64);
            float p2 = 0.f;
            #pragma unroll
            for (int q = 0; q < 16; ++q) {
                float4 v = pr[q];
                p2 += v.x*v.x + v.y*v.y + v.z*v.z + v.w*v.w;
            }
            float m = fmaxf(mv + p2, 0.0f);
            md_out[n*P_ + gp] = m;
            acts[n*P_ + gp]   = logf((m + 1.0f) / (m + EPS));
        }
    }
}

// ---------------- Kernel 3: logits = acts @ last_w^T, one wave per output ----------------
__global__ __launch_bounds__(256) void k3_logits(const float* __restrict__ acts,
    const float* __restrict__ last_w, float* __restrict__ out)
{
    const int wid  = (blockIdx.x * 256 + threadIdx.x) >> 6;  // 0..6399
    const int lane = threadIdx.x & 63;
    const int n    = wid / NCLS;
    const int cls  = wid - n * NCLS;

    const float4* a = (const float4*)(acts + (size_t)n*P_);
    const float4* w = (const float4*)(last_w + (size_t)cls*P_);

    float acc = 0.f;
    #pragma unroll
    for (int it = 0; it < 8; ++it) {
        int idx = it*64 + lane;          // float4 index, 0..511
        if (idx < P_/4) {
            float4 av = a[idx]; float4 wv = w[idx];
            acc += av.x*wv.x + av.y*wv.y + av.z*wv.z + av.w*wv.w;
        }
    }
    #pragma unroll
    for (int off = 32; off > 0; off >>= 1)
        acc += __shfl_down(acc, off);
    if (lane == 0)
        out[n*NCLS + cls] = acc;
}

extern "C" void kernel_launch(void* const* d_in, const int* in_sizes, int n_in,
                              void* d_out, int out_size, void* d_ws, size_t ws_size,
                              hipStream_t stream)
{
    const float* x      = (const float*)d_in[0];
    const float* W1     = (const float*)d_in[1];
    const float* b1     = (const float*)d_in[2];
    const float* W2     = (const float*)d_in[3];
    const float* b2     = (const float*)d_in[4];
    const float* proto  = (const float*)d_in[5];
    const float* last_w = (const float*)d_in[6];

    float* out = (float*)d_out;   // [32*200] logits, then [32*2000] min_dist

    // ws layout: fTh 2MB | fTl 2MB | x2buf 64KB | acts 256KB
    unsigned short* fTh = (unsigned short*)d_ws;
    unsigned short* fTl = fTh + (size_t)N_*L_*CP;
    float* x2buf = (float*)(fTl + (size_t)N_*L_*CP);
    float* acts  = x2buf + (size_t)N_*L_;

    k1_conv  <<<dim3(16, 32), 256, 0, stream>>>(x, W1, b1, W2, b2, fTh, fTl, x2buf);
    k2_dist  <<<dim3(16, 32), 256, 0, stream>>>(fTh, fTl, x2buf, proto, out + N_*NCLS, acts);
    k3_logits<<<1600,         256, 0, stream>>>(acts, last_w, out);
}